// Round 3
// baseline (197.347 us; speedup 1.0000x reference)
//
#include <hip/hip_runtime.h>
#include <cstddef>

#define N_PIX 4096
#define HW 64
#define LOG2E 1.4426950408889634f
#define SHIFT2 28.8539008177793f   // 20 * log2(e)

typedef __attribute__((ext_vector_type(8))) short bf16x8;
typedef __attribute__((ext_vector_type(4))) float f32x4;

static __device__ __forceinline__ unsigned short f2bf(float f) {
    union { float f; unsigned u; } v; v.f = f;
    unsigned r = v.u + 0x7fffu + ((v.u >> 16) & 1u);   // RNE
    return (unsigned short)(r >> 16);
}
static __device__ __forceinline__ float bf2f(unsigned short s) {
    union { unsigned u; float f; } v; v.u = (unsigned)s << 16;
    return v.f;
}
// (bf16(hi)<<16)|bf16(lo), truncating: one v_perm_b32
static __device__ __forceinline__ unsigned pack_bf16_trunc(float lo, float hi) {
    union { float f; unsigned u; } a, b; a.f = hi; b.f = lo;
    return __builtin_amdgcn_perm(a.u, b.u, 0x07060302u);
}

// ---------------------------------------------------------------------------
// x [b][256 ci][4096 px] fp32  ->  xbf [b][4096 px][256 ci] bf16
// ---------------------------------------------------------------------------
__global__ __launch_bounds__(256) void x_transpose(
    const float* __restrict__ x, unsigned short* __restrict__ xbf)
{
    __shared__ unsigned short Ts[64][72];
    const int tid = threadIdx.x;
    const int px0 = blockIdx.x * 64, ci0 = blockIdx.y * 64, b = blockIdx.z;
    const float* xb = x + ((size_t)b * 256 + ci0) * N_PIX;

#pragma unroll
    for (int r = 0; r < 4; ++r) {
        int c = r * 16 + (tid >> 4);
        int p4 = (tid & 15) * 4;
        float4 v = *(const float4*)&xb[(size_t)c * N_PIX + px0 + p4];
        Ts[c][p4 + 0] = f2bf(v.x);
        Ts[c][p4 + 1] = f2bf(v.y);
        Ts[c][p4 + 2] = f2bf(v.z);
        Ts[c][p4 + 3] = f2bf(v.w);
    }
    __syncthreads();
#pragma unroll
    for (int r = 0; r < 2; ++r) {
        int id = tid * 2 + r;
        int p = id >> 3, c8 = (id & 7) * 8;
        ushort4 lo, hi;
        lo.x = Ts[c8 + 0][p]; lo.y = Ts[c8 + 1][p];
        lo.z = Ts[c8 + 2][p]; lo.w = Ts[c8 + 3][p];
        hi.x = Ts[c8 + 4][p]; hi.y = Ts[c8 + 5][p];
        hi.z = Ts[c8 + 6][p]; hi.w = Ts[c8 + 7][p];
        size_t off = ((size_t)b * N_PIX + px0 + p) * 256 + ci0 + c8;
        *(ushort4*)&xbf[off]     = lo;
        *(ushort4*)&xbf[off + 4] = hi;
    }
}

// ---------------------------------------------------------------------------
// Weights -> wAll [kb 0..71][320 rows][32 kin] bf16 (A-frag order).
// Rows: 0..255 wv, 256..287 wq (scaled by log2e), 288..319 wk.
// ---------------------------------------------------------------------------
__global__ __launch_bounds__(256) void w_transform(
    const float* __restrict__ wq, const float* __restrict__ wk,
    const float* __restrict__ wv, unsigned short* __restrict__ wAll)
{
    int gid = blockIdx.x * 256 + threadIdx.x;
    if (gid >= 72 * 320 * 4) return;
    int part = gid & 3;
    int m = (gid >> 2) % 320;
    int kb = gid / 1280;
    int t = kb >> 3;
    int ci0 = (kb & 7) * 32 + part * 8;
    const float* src; int co; float sc = 1.f;
    if (m < 256)      { src = wv; co = m; }
    else if (m < 288) { src = wq; co = m - 256; sc = LOG2E; }
    else              { src = wk; co = m - 288; }
    ushort4 lo, hi;
    lo.x = f2bf(sc * src[((size_t)co * 256 + ci0 + 0) * 9 + t]);
    lo.y = f2bf(sc * src[((size_t)co * 256 + ci0 + 1) * 9 + t]);
    lo.z = f2bf(sc * src[((size_t)co * 256 + ci0 + 2) * 9 + t]);
    lo.w = f2bf(sc * src[((size_t)co * 256 + ci0 + 3) * 9 + t]);
    hi.x = f2bf(sc * src[((size_t)co * 256 + ci0 + 4) * 9 + t]);
    hi.y = f2bf(sc * src[((size_t)co * 256 + ci0 + 5) * 9 + t]);
    hi.z = f2bf(sc * src[((size_t)co * 256 + ci0 + 6) * 9 + t]);
    hi.w = f2bf(sc * src[((size_t)co * 256 + ci0 + 7) * 9 + t]);
    size_t off = ((size_t)kb * 320 + m) * 32 + part * 8;
    *(ushort4*)&wAll[off]     = lo;
    *(ushort4*)&wAll[off + 4] = hi;
}

// ---------------------------------------------------------------------------
// Conv implicit GEMM v5: one block per image ROW (64 px) per batch; ALL 320
// output rows in one block (512 thr, 8 waves; wave = 80 rows x 32 px).
// The 3 input rows (y-1,y,y+1) x 66 halo-cols are staged into LDS in TWO
// ci-halves of 128 (LDS = 3*66*136 shorts = 53.9 KB, safe; row stride 136
// -> 8-dense bank pattern on reads and writes, no extra conflicts).
// Per half: 18 pure ds_read+MFMA steps, NO barriers, NO global B loads.
// Half-1 global loads are issued into registers BEFORE half-0 compute, so
// HBM/L2 latency hides under 360 MFMAs.  A-frags (wAll, L2-hot) register
// double-buffered one step ahead.  3 barriers total.
// kb mapping identical to v3 (half0: kb%8 in 0..3, half1: 4..7).
// ---------------------------------------------------------------------------
__global__ __launch_bounds__(512, 2) void conv_gemm_v5(
    const unsigned short* __restrict__ xbf, const unsigned short* __restrict__ wAll,
    const float* __restrict__ bq, const float* __restrict__ bk,
    const float* __restrict__ bv,
    unsigned short* __restrict__ vbf, unsigned short* __restrict__ qt,
    unsigned short* __restrict__ kt)
{
    __shared__ unsigned short Xs[3 * 66 * 136];   // 53856 B

    const int tid = threadIdx.x;
    const int w = tid >> 6, lane = tid & 63, quad = lane >> 4, l15 = lane & 15;
    const int y = blockIdx.x;      // image row
    const int b = blockIdx.y;
    const int r0 = (w >> 1) * 80;  // output-channel base of this wave
    const int p0 = (w & 1) * 32;   // pixel base of this wave

    const unsigned short* xb = xbf + (size_t)b * N_PIX * 256;
    const unsigned short* aBase = wAll + ((size_t)(r0 + l15) * 32 + quad * 8);

    // ---- staging thread mapping: col 0..63, granule pair (2 x 8 shorts)
    const int scol = tid >> 3;
    const int sg2  = (tid & 7) * 2;

    bf16x8 S[3][2];
    auto stage_load = [&](int h) {
#pragma unroll
        for (int ry = 0; ry < 3; ++ry) {
            int gy = y + ry - 1;
            if ((unsigned)gy < 64u) {
                const unsigned short* s =
                    xb + ((size_t)(gy * 64 + scol) * 256 + h * 128 + sg2 * 8);
                S[ry][0] = *(const bf16x8*)&s[0];
                S[ry][1] = *(const bf16x8*)&s[8];
            } else {
                S[ry][0] = (bf16x8){0,0,0,0,0,0,0,0};
                S[ry][1] = (bf16x8){0,0,0,0,0,0,0,0};
            }
        }
    };
    auto stage_store = [&]() {
#pragma unroll
        for (int ry = 0; ry < 3; ++ry) {
            *(bf16x8*)&Xs[(ry * 66 + scol + 1) * 136 + sg2 * 8]     = S[ry][0];
            *(bf16x8*)&Xs[(ry * 66 + scol + 1) * 136 + sg2 * 8 + 8] = S[ry][1];
        }
    };

    bf16x8 afA[2][5], afB[2][5];
    auto load_a = [&](int kb, bf16x8 (&af)[2][5]) {
        const unsigned short* p = aBase + (size_t)kb * 10240;
#pragma unroll
        for (int kl = 0; kl < 2; ++kl)
#pragma unroll
            for (int cb = 0; cb < 5; ++cb)
                af[kl][cb] = *(const bf16x8*)&p[kl * 10240 + cb * 512];
    };

    bf16x8 bfA[2][2], bfB[2][2];
    auto load_bf = [&](int t, int q2, bf16x8 (&bf)[2][2]) {
        int ty = t / 3;                     // compile-time after unroll
        int dx = t - ty * 3 - 1;
#pragma unroll
        for (int kl = 0; kl < 2; ++kl)
#pragma unroll
            for (int jb = 0; jb < 2; ++jb) {
                int sx = p0 + jb * 16 + l15 + dx + 1;
                int cg = q2 * 8 + kl * 4 + quad;
                bf[kl][jb] = *(const bf16x8*)&Xs[(ty * 66 + sx) * 136 + cg * 8];
            }
    };

    f32x4 acc[5][2];
#pragma unroll
    for (int cb = 0; cb < 5; ++cb)
#pragma unroll
        for (int jb = 0; jb < 2; ++jb) acc[cb][jb] = (f32x4){0.f, 0.f, 0.f, 0.f};

    auto mfma_step = [&](bf16x8 (&af)[2][5], bf16x8 (&bf)[2][2]) {
#pragma unroll
        for (int kl = 0; kl < 2; ++kl)
#pragma unroll
            for (int cb = 0; cb < 5; ++cb)
#pragma unroll
                for (int jb = 0; jb < 2; ++jb)
                    acc[cb][jb] = __builtin_amdgcn_mfma_f32_16x16x32_bf16(
                        af[kl][cb], bf[kl][jb], acc[cb][jb], 0, 0, 0);
    };

    // ---- prologue: stage half 0; zero halo columns (persist across halves)
    stage_load(0);
    load_a(0, afA);
    stage_store();
    if (tid < 96) {
        int ry = tid >> 5, rem = tid & 31;
        int sx = (rem >> 4) ? 65 : 0;
        int cg = rem & 15;
        *(bf16x8*)&Xs[(ry * 66 + sx) * 136 + cg * 8] = (bf16x8){0,0,0,0,0,0,0,0};
    }
    __syncthreads();

    stage_load(1);              // issue half-1 globals now; hide under compute

    // ---- half 0: 18 steps (t 0..8, q2 0..1), kb = t*8 + q2*2
    load_bf(0, 0, bfA);
#pragma unroll
    for (int s = 0; s < 18; s += 2) {
        const int t1 = (s + 1) >> 1, q1 = (s + 1) & 1;
        load_a(t1 * 8 + q1 * 2, afB);
        load_bf(t1, q1, bfB);
        mfma_step(afA, bfA);
        if (s + 2 < 18) {
            const int t2 = (s + 2) >> 1, q2_ = (s + 2) & 1;
            load_a(t2 * 8 + q2_ * 2, afA);
            load_bf(t2, q2_, bfA);
        } else {
            load_a(4, afA);     // half 1, step 0: kb = 0*8 + 4
        }
        mfma_step(afB, bfB);
    }

    __syncthreads();            // all half-0 LDS reads done
    stage_store();              // write half 1
    __syncthreads();

    // ---- half 1: kb = t*8 + 4 + q2*2
    load_bf(0, 0, bfA);
#pragma unroll
    for (int s = 0; s < 18; s += 2) {
        const int t1 = (s + 1) >> 1, q1 = (s + 1) & 1;
        load_a(t1 * 8 + 4 + q1 * 2, afB);
        load_bf(t1, q1, bfB);
        mfma_step(afA, bfA);
        if (s + 2 < 18) {
            const int t2 = (s + 2) >> 1, q2_ = (s + 2) & 1;
            load_a(t2 * 8 + 4 + q2_ * 2, afA);
            load_bf(t2, q2_, bfA);
        }
        mfma_step(afB, bfB);
    }

    // ---- epilogue: rows <256 -> V, 256..287 -> Q (log2e-scaled), 288.. -> K
#pragma unroll
    for (int cb = 0; cb < 5; ++cb) {
        int cBase = r0 + cb * 16 + quad * 4;
#pragma unroll
        for (int r = 0; r < 4; ++r) {
            int c = cBase + r;
            if (c < 256) {
                float bias = bv[c];
#pragma unroll
                for (int jb = 0; jb < 2; ++jb) {
                    int px = y * 64 + p0 + jb * 16 + l15;
                    vbf[((size_t)b * 256 + c) * N_PIX + px] = f2bf(acc[cb][jb][r] + bias);
                }
            } else if (c < 288) {
                float bias = bq[c - 256] * LOG2E;
#pragma unroll
                for (int jb = 0; jb < 2; ++jb) {
                    int px = y * 64 + p0 + jb * 16 + l15;
                    qt[((size_t)b * N_PIX + px) * 32 + (c - 256)] = f2bf(acc[cb][jb][r] + bias);
                }
            } else {
                float bias = bk[c - 288];
#pragma unroll
                for (int jb = 0; jb < 2; ++jb) {
                    int px = y * 64 + p0 + jb * 16 + l15;
                    kt[((size_t)b * N_PIX + px) * 32 + (c - 288)] = f2bf(acc[cb][jb][r] + bias);
                }
            }
        }
    }
}

// ---------------------------------------------------------------------------
// MFMA flash attention — j-tile 128, single barrier/iter, Pfrag ping-pong.
// qt pre-scaled by log2e; shift folded into MFMA C-init; P packed with
// v_perm_b32 (truncating bf16).
// ---------------------------------------------------------------------------
__global__ __launch_bounds__(256, 2) void fused_attn_mfma(
    const unsigned short* __restrict__ qt, const unsigned short* __restrict__ kt,
    const unsigned short* __restrict__ vbf,
    unsigned short* __restrict__ Abuf, float* __restrict__ lbuf, int iRange)
{
    const int tid  = threadIdx.x;
    const int w    = tid >> 6;
    const int lane = tid & 63;
    const int quad = lane >> 4;
    const int l15  = lane & 15;
    const int j0   = blockIdx.x * 128;
    const int b    = blockIdx.y;
    const int sp   = blockIdx.z;
    const int iBeg = sp * iRange;
    const int NI   = iRange / 64;

    const unsigned short* qtb = qt + (size_t)b * N_PIX * 32;
    const unsigned short* ktb = kt + (size_t)b * N_PIX * 32;
    const unsigned short* vb  = vbf + (size_t)b * 256 * N_PIX;

    __shared__ unsigned Pfrag[2][4096];   // 32 KB ping-pong (dwords)
    __shared__ float lred[4][128];

    bf16x8 kf[8];
#pragma unroll
    for (int jb = 0; jb < 8; ++jb)
        kf[jb] = *(const bf16x8*)&ktb[((size_t)(j0 + jb * 16 + l15)) * 32 + quad * 8];

    f32x4 acc[4][8];
#pragma unroll
    for (int cb = 0; cb < 4; ++cb)
#pragma unroll
        for (int jb = 0; jb < 8; ++jb)
            acc[cb][jb] = (f32x4){0.f, 0.f, 0.f, 0.f};

    float lpart[8] = {0.f, 0.f, 0.f, 0.f, 0.f, 0.f, 0.f, 0.f};

    const int wFrag = w >> 1;
    const int wL    = ((w & 1) << 5) + ((quad >> 1) << 4) + l15;
    const int wEl2  = (quad & 1) << 1;   // dword offset 0 or 2

    bf16x8 va[2][4];

    auto s_phase = [&](bf16x8 qa, int buf) {
#pragma unroll
        for (int jb = 0; jb < 8; ++jb) {
            f32x4 s = __builtin_amdgcn_mfma_f32_16x16x32_bf16(
                qa, kf[jb], (f32x4){-SHIFT2, -SHIFT2, -SHIFT2, -SHIFT2}, 0, 0, 0);
            float p0 = __builtin_amdgcn_exp2f(s[0]);
            float p1 = __builtin_amdgcn_exp2f(s[1]);
            float p2 = __builtin_amdgcn_exp2f(s[2]);
            float p3 = __builtin_amdgcn_exp2f(s[3]);
            lpart[jb] += (p0 + p1) + (p2 + p3);
            unsigned u0 = pack_bf16_trunc(p0, p1);
            unsigned u1 = pack_bf16_trunc(p2, p3);
            unsigned base = (((jb << 1) + wFrag) * 64 + wL) * 4 + wEl2;
            Pfrag[buf][base]     = u0;
            Pfrag[buf][base + 1] = u1;
        }
    };

    auto load_qa = [&](int i0) {
        return *(const bf16x8*)&qtb[((size_t)(i0 + w * 16 + l15)) * 32 + quad * 8];
    };
    auto load_va = [&](int i0) {
#pragma unroll
        for (int ks = 0; ks < 2; ++ks)
#pragma unroll
            for (int cb = 0; cb < 4; ++cb)
                va[ks][cb] = *(const bf16x8*)&vb[((size_t)(w * 64 + cb * 16 + l15)) * N_PIX
                                                 + i0 + ks * 32 + quad * 8];
    };

    // prologue
    load_va(iBeg);
    s_phase(load_qa(iBeg), 0);

    for (int n = 0; n < NI; ++n) {
        __syncthreads();               // P[n&1] ready for all waves
        const bool hasN = (n + 1 < NI);
        const int inext = iBeg + (n + 1) * 64;
        bf16x8 qaN;
        if (hasN) qaN = load_qa(inext);

        // ---- O(n): reads Pfrag[n&1] + va (loaded for iter n)
#pragma unroll
        for (int ks = 0; ks < 2; ++ks) {
            bf16x8 pb[8];
#pragma unroll
            for (int jb = 0; jb < 8; ++jb)
                pb[jb] = *(const bf16x8*)&Pfrag[n & 1][(((jb << 1) + ks) * 64 + lane) * 4];
#pragma unroll
            for (int cb = 0; cb < 4; ++cb)
#pragma unroll
                for (int jb = 0; jb < 8; ++jb)
                    acc[cb][jb] = __builtin_amdgcn_mfma_f32_16x16x32_bf16(
                        va[ks][cb], pb[jb], acc[cb][jb], 0, 0, 0);
        }

        // ---- prefetch va(n+1) then S(n+1) into other buffer
        if (hasN) {
            load_va(inext);
            s_phase(qaN, (n + 1) & 1);
        }
    }

    // ---- l reduction
#pragma unroll
    for (int jb = 0; jb < 8; ++jb) {
        float v = lpart[jb];
        v += __shfl_xor(v, 16, 64);
        v += __shfl_xor(v, 32, 64);
        lpart[jb] = v;
    }
    if (lane < 16) {
#pragma unroll
        for (int jb = 0; jb < 8; ++jb)
            lred[w][jb * 16 + l15] = lpart[jb];
    }
    __syncthreads();
    if (tid < 128) {
        float s = lred[0][tid] + lred[1][tid] + lred[2][tid] + lred[3][tid];
        lbuf[((size_t)sp * 4 + b) * N_PIX + j0 + tid] = s;
    }

    // ---- A partial store (bf16, unnormalized)
    unsigned short* Ab = Abuf + ((size_t)sp * 4 + b) * 256 * N_PIX;
#pragma unroll
    for (int cb = 0; cb < 4; ++cb) {
        int c = w * 64 + cb * 16 + quad * 4;
#pragma unroll
        for (int jb = 0; jb < 8; ++jb) {
            int j = j0 + jb * 16 + l15;
#pragma unroll
            for (int r = 0; r < 4; ++r)
                Ab[(size_t)(c + r) * N_PIX + j] = f2bf(acc[cb][jb][r]);
        }
    }
}

// ---------------------------------------------------------------------------
// combine: out = x + g * (sum_s A_s) / (sum_s l_s);  A is bf16.
// ---------------------------------------------------------------------------
__global__ __launch_bounds__(256) void combine_kernel(
    const unsigned short* __restrict__ A, const float* __restrict__ L,
    const float* __restrict__ x, const float* __restrict__ gamma,
    float* __restrict__ out, int split)
{
    const size_t CH = (size_t)4 * 256 * N_PIX;
    size_t flat = ((size_t)blockIdx.x * 256 + threadIdx.x) * 8;
    int j = (int)(flat & (N_PIX - 1));
    int b = (int)(flat >> 20);

    float a[8] = {0.f, 0.f, 0.f, 0.f, 0.f, 0.f, 0.f, 0.f};
    float l[8] = {0.f, 0.f, 0.f, 0.f, 0.f, 0.f, 0.f, 0.f};
    for (int s = 0; s < split; ++s) {
        ushort4 av0 = *(const ushort4*)&A[flat + (size_t)s * CH];
        ushort4 av1 = *(const ushort4*)&A[flat + (size_t)s * CH + 4];
        a[0] += bf2f(av0.x); a[1] += bf2f(av0.y); a[2] += bf2f(av0.z); a[3] += bf2f(av0.w);
        a[4] += bf2f(av1.x); a[5] += bf2f(av1.y); a[6] += bf2f(av1.z); a[7] += bf2f(av1.w);
        float4 l0 = *(const float4*)&L[((size_t)s * 4 + b) * N_PIX + j];
        float4 l1 = *(const float4*)&L[((size_t)s * 4 + b) * N_PIX + j + 4];
        l[0] += l0.x; l[1] += l0.y; l[2] += l0.z; l[3] += l0.w;
        l[4] += l1.x; l[5] += l1.y; l[6] += l1.z; l[7] += l1.w;
    }
    float g = gamma[0];
    float4 x0 = *(const float4*)&x[flat];
    float4 x1 = *(const float4*)&x[flat + 4];
    float4 o0, o1;
    o0.x = x0.x + g * a[0] / l[0];
    o0.y = x0.y + g * a[1] / l[1];
    o0.z = x0.z + g * a[2] / l[2];
    o0.w = x0.w + g * a[3] / l[3];
    o1.x = x1.x + g * a[4] / l[4];
    o1.y = x1.y + g * a[5] / l[5];
    o1.z = x1.z + g * a[6] / l[6];
    o1.w = x1.w + g * a[7] / l[7];
    *(float4*)&out[flat]     = o0;
    *(float4*)&out[flat + 4] = o1;
}

// ---------------------------------------------------------------------------
extern "C" void kernel_launch(void* const* d_in, const int* in_sizes, int n_in,
                              void* d_out, int out_size, void* d_ws, size_t ws_size,
                              hipStream_t stream)
{
    const float* x     = (const float*)d_in[0];
    const float* wq    = (const float*)d_in[1];
    const float* bq    = (const float*)d_in[2];
    const float* wk    = (const float*)d_in[3];
    const float* bk    = (const float*)d_in[4];
    const float* wv    = (const float*)d_in[5];
    const float* bv    = (const float*)d_in[6];
    const float* gamma = (const float*)d_in[7];
    float* out = (float*)d_out;

    const size_t szQTel  = (size_t)4 * N_PIX * 32;        // elements (ushort)
    const size_t szVBFel = (size_t)4 * 256 * N_PIX;
    const size_t szXBFel = (size_t)4 * N_PIX * 256;
    const size_t szWel   = (size_t)72 * 320 * 32;
    const size_t fixedB  = (2 * szQTel + szVBFel + szXBFel + szWel) * 2;

    int split = 4;
    while (split > 1) {
        size_t need = fixedB
                    + (size_t)split * 4 * 256 * N_PIX * 2    // A bf16
                    + (size_t)split * 4 * N_PIX * 4;         // l fp32
        if (need <= ws_size) break;
        split >>= 1;
    }

    unsigned short* Abuf = (unsigned short*)d_ws;
    float* lbuf = (float*)(Abuf + (size_t)split * 4 * 256 * N_PIX);
    unsigned short* qt   = (unsigned short*)(lbuf + (size_t)split * 4 * N_PIX);
    unsigned short* kt   = qt + szQTel;
    unsigned short* vbf  = kt + szQTel;
    unsigned short* xbf  = vbf + szVBFel;
    unsigned short* wAll = xbf + szXBFel;

    x_transpose<<<dim3(N_PIX / 64, 4, 4), 256, 0, stream>>>(x, xbf);
    w_transform<<<dim3((72 * 320 * 4 + 255) / 256), 256, 0, stream>>>(wq, wk, wv, wAll);

    conv_gemm_v5<<<dim3(HW, 4), 512, 0, stream>>>(
        xbf, wAll, bq, bk, bv, vbf, qt, kt);

    fused_attn_mfma<<<dim3(N_PIX / 128, 4, split), 256, 0, stream>>>(
        qt, kt, vbf, Abuf, lbuf, N_PIX / split);

    combine_kernel<<<dim3((4 * 256 * N_PIX) / (256 * 8)), 256, 0, stream>>>(
        Abuf, lbuf, x, gamma, out, split);
}

// Round 4
// 178.706 us; speedup vs baseline: 1.1043x; 1.1043x over previous
//
#include <hip/hip_runtime.h>
#include <cstddef>

#define N_PIX 4096
#define HW 64
#define LOG2E 1.4426950408889634f
#define SHIFT2 28.8539008177793f   // 20 * log2(e)

typedef __attribute__((ext_vector_type(8))) short bf16x8;
typedef __attribute__((ext_vector_type(4))) float f32x4;
typedef unsigned int u32;

static __device__ __forceinline__ unsigned short f2bf(float f) {
    union { float f; unsigned u; } v; v.f = f;
    unsigned r = v.u + 0x7fffu + ((v.u >> 16) & 1u);   // RNE
    return (unsigned short)(r >> 16);
}
static __device__ __forceinline__ float bf2f(unsigned short s) {
    union { unsigned u; float f; } v; v.u = (unsigned)s << 16;
    return v.f;
}
// (bf16(hi)<<16)|bf16(lo), truncating: one v_perm_b32
static __device__ __forceinline__ unsigned pack_bf16_trunc(float lo, float hi) {
    union { float f; unsigned u; } a, b; a.f = hi; b.f = lo;
    return __builtin_amdgcn_perm(a.u, b.u, 0x07060302u);
}
// async global->LDS, 16 B per lane; LDS dest is WAVE-UNIFORM base + lane*16
static __device__ __forceinline__ void gll16(const void* g, void* l) {
    __builtin_amdgcn_global_load_lds(
        (const __attribute__((address_space(1))) u32*)g,
        (__attribute__((address_space(3))) u32*)l, 16, 0, 0);
}

// ---------------------------------------------------------------------------
// x [b][256 ci][4096 px] fp32  ->  xbf [b][4096 px][256 ci] bf16
// ---------------------------------------------------------------------------
__global__ __launch_bounds__(256) void x_transpose(
    const float* __restrict__ x, unsigned short* __restrict__ xbf)
{
    __shared__ unsigned short Ts[64][72];
    const int tid = threadIdx.x;
    const int px0 = blockIdx.x * 64, ci0 = blockIdx.y * 64, b = blockIdx.z;
    const float* xb = x + ((size_t)b * 256 + ci0) * N_PIX;

#pragma unroll
    for (int r = 0; r < 4; ++r) {
        int c = r * 16 + (tid >> 4);
        int p4 = (tid & 15) * 4;
        float4 v = *(const float4*)&xb[(size_t)c * N_PIX + px0 + p4];
        Ts[c][p4 + 0] = f2bf(v.x);
        Ts[c][p4 + 1] = f2bf(v.y);
        Ts[c][p4 + 2] = f2bf(v.z);
        Ts[c][p4 + 3] = f2bf(v.w);
    }
    __syncthreads();
#pragma unroll
    for (int r = 0; r < 2; ++r) {
        int id = tid * 2 + r;
        int p = id >> 3, c8 = (id & 7) * 8;
        ushort4 lo, hi;
        lo.x = Ts[c8 + 0][p]; lo.y = Ts[c8 + 1][p];
        lo.z = Ts[c8 + 2][p]; lo.w = Ts[c8 + 3][p];
        hi.x = Ts[c8 + 4][p]; hi.y = Ts[c8 + 5][p];
        hi.z = Ts[c8 + 6][p]; hi.w = Ts[c8 + 7][p];
        size_t off = ((size_t)b * N_PIX + px0 + p) * 256 + ci0 + c8;
        *(ushort4*)&xbf[off]     = lo;
        *(ushort4*)&xbf[off + 4] = hi;
    }
}

// ---------------------------------------------------------------------------
// Weights -> wAll [kb 0..71][320 rows][32 kin] bf16 (A-frag order).
// Rows: 0..255 wv, 256..287 wq (scaled by log2e), 288..319 wk.
// Also zeroes the 512-B zero page used by conv staging for halo taps.
// ---------------------------------------------------------------------------
__global__ __launch_bounds__(256) void w_transform(
    const float* __restrict__ wq, const float* __restrict__ wk,
    const float* __restrict__ wv, unsigned short* __restrict__ wAll,
    unsigned short* __restrict__ zp)
{
    int gid = blockIdx.x * 256 + threadIdx.x;
    if (gid < 256) zp[gid] = 0;
    if (gid >= 72 * 320 * 4) return;
    int part = gid & 3;
    int m = (gid >> 2) % 320;
    int kb = gid / 1280;
    int t = kb >> 3;
    int ci0 = (kb & 7) * 32 + part * 8;
    const float* src; int co; float sc = 1.f;
    if (m < 256)      { src = wv; co = m; }
    else if (m < 288) { src = wq; co = m - 256; sc = LOG2E; }
    else              { src = wk; co = m - 288; }
    ushort4 lo, hi;
    lo.x = f2bf(sc * src[((size_t)co * 256 + ci0 + 0) * 9 + t]);
    lo.y = f2bf(sc * src[((size_t)co * 256 + ci0 + 1) * 9 + t]);
    lo.z = f2bf(sc * src[((size_t)co * 256 + ci0 + 2) * 9 + t]);
    lo.w = f2bf(sc * src[((size_t)co * 256 + ci0 + 3) * 9 + t]);
    hi.x = f2bf(sc * src[((size_t)co * 256 + ci0 + 4) * 9 + t]);
    hi.y = f2bf(sc * src[((size_t)co * 256 + ci0 + 5) * 9 + t]);
    hi.z = f2bf(sc * src[((size_t)co * 256 + ci0 + 6) * 9 + t]);
    hi.w = f2bf(sc * src[((size_t)co * 256 + ci0 + 7) * 9 + t]);
    size_t off = ((size_t)kb * 320 + m) * 32 + part * 8;
    *(ushort4*)&wAll[off]     = lo;
    *(ushort4*)&wAll[off + 4] = hi;
}

// ---------------------------------------------------------------------------
// Conv implicit GEMM v6: T3+T4 pipeline (global_load_lds + counted vmcnt +
// raw s_barrier).  v2/v3/v5 all pinned at ~60us because in-loop A-loads
// went global->VGPR and the compiler serialized them (v5 VGPR_Count=60
// proves the declared double-buffers were discarded).  Here BOTH operands
// are DMA'd to LDS (no VGPR round trip, nothing to discard), 3 buffers,
// 2 steps in flight, per-wave vmcnt(4/3) -- never 0 in the loop.
// Grid (64 y, 2 row-halves, 4 b) = 512 blocks x 256 thr (2 blocks/CU).
// Block = 160 GEMM rows x 64 px; wave = 80 rows x 32 px; acc[5][2].
// Per step kb (K=32): A 10 KB + B 4 KB staged as 14 x 1KB gll chunks;
// LDS XOR-swizzle o^=((o>>7)&7)<<4 applied to pre-swizzled global source
// AND ds_read address (same involution) -> frag reads 2-way (free).
// OOB halo lanes read a zero page.  K-order identical to v3.
// ---------------------------------------------------------------------------
__global__ __launch_bounds__(256, 2) void conv_gemm_v6(
    const unsigned short* __restrict__ xbf, const unsigned short* __restrict__ wAll,
    const float* __restrict__ bq, const float* __restrict__ bk,
    const float* __restrict__ bv, const unsigned short* __restrict__ zpage,
    unsigned short* __restrict__ vbf, unsigned short* __restrict__ qt,
    unsigned short* __restrict__ kt)
{
    __shared__ unsigned short Bl[3 * 7168];   // 3 bufs x 14336 B = 42 KB

    const int tid = threadIdx.x;
    const int w = tid >> 6, lane = tid & 63, quad = lane >> 4, l15 = lane & 15;
    const int y = blockIdx.x, rh = blockIdx.y, b = blockIdx.z;
    const int rg = w >> 1;          // 80-row group within the 160
    const int pxh = w & 1;          // 32-px half

    const unsigned short* xb = xbf + (size_t)b * N_PIX * 256;
    const unsigned short* aSrc = wAll + (size_t)rh * 160 * 32;   // +kb*10240

    // stage step kb into buffer buf.  chunk c = r*4+w: c<10 -> A byte off
    // c*1024; c in 10..13 -> B byte off (c-10)*1024.  waves 0,1: 4 chunks;
    // waves 2,3: 3 chunks.
    auto stage = [&](int kb, int buf) {
        const int t_ = kb >> 3;
        const int ty = t_ / 3;
        const int dy = ty - 1, dx = t_ - ty * 3 - 1;
        const int gy = y + dy;
        const bool rowOK = ((unsigned)gy < 64u);
        const int ci0 = (kb & 7) * 32;
        const unsigned short* aS = aSrc + (size_t)kb * 10240;
        unsigned short* tile = &Bl[buf * 7168];
#pragma unroll
        for (int r = 0; r < 4; ++r) {
            const int c = r * 4 + w;
            if (r == 3 && w >= 2) continue;      // wave-uniform skip
            if (c < 10) {
                int o = c * 1024 + lane * 16;
                int u = o ^ (((o >> 7) & 7) << 4);
                gll16(aS + (u >> 1), tile + c * 512);
            } else {
                int o = (c - 10) * 1024 + lane * 16;
                int u = o ^ (((o >> 7) & 7) << 4);
                int px = u >> 6, k16 = (u >> 4) & 3;
                int gx = px + dx;
                const unsigned short* src =
                    (rowOK && (unsigned)gx < 64u)
                        ? xb + ((size_t)(gy * 64 + gx) * 256 + ci0 + k16 * 8)
                        : zpage;
                gll16(src, tile + 5120 + (c - 10) * 512);
            }
        }
    };

    f32x4 acc[5][2];
#pragma unroll
    for (int cb = 0; cb < 5; ++cb)
#pragma unroll
        for (int jb = 0; jb < 2; ++jb) acc[cb][jb] = (f32x4){0.f, 0.f, 0.f, 0.f};

    // ---- prologue: fill pipeline 2 deep
    stage(0, 0);
    stage(1, 1);
    if (w < 2) asm volatile("s_waitcnt vmcnt(4)" ::: "memory");
    else       asm volatile("s_waitcnt vmcnt(3)" ::: "memory");
    __builtin_amdgcn_s_barrier();
    __builtin_amdgcn_sched_barrier(0);

    int buf = 0;
    for (int kb = 0; kb < 72; ++kb) {
        int nb = buf + 1; if (nb == 3) nb = 0;
        int pb = nb + 1;  if (pb == 3) pb = 0;
        const bool more2 = (kb + 2 < 72);
        const bool more1 = (kb + 1 < 72);
        if (more2) stage(kb + 2, pb);

        // ---- frag reads from buf (swizzled), then MFMA
        const int bb = buf * 7168;
        bf16x8 af[5], bfr[2];
#pragma unroll
        for (int cb = 0; cb < 5; ++cb) {
            int sr = rg * 80 + cb * 16 + l15;
            int u = sr * 64 + quad * 16;
            u ^= ((u >> 7) & 7) << 4;
            af[cb] = *(const bf16x8*)&Bl[bb + (u >> 1)];
        }
#pragma unroll
        for (int jb = 0; jb < 2; ++jb) {
            int px = pxh * 32 + jb * 16 + l15;
            int u = px * 64 + quad * 16;
            u ^= ((u >> 7) & 7) << 4;
            bfr[jb] = *(const bf16x8*)&Bl[bb + 5120 + (u >> 1)];
        }
        __builtin_amdgcn_s_setprio(1);
#pragma unroll
        for (int cb = 0; cb < 5; ++cb)
#pragma unroll
            for (int jb = 0; jb < 2; ++jb)
                acc[cb][jb] = __builtin_amdgcn_mfma_f32_16x16x32_bf16(
                    af[cb], bfr[jb], acc[cb][jb], 0, 0, 0);
        __builtin_amdgcn_s_setprio(0);

        // ---- counted wait: leave THIS iteration's issues in flight
        if (more2) {
            if (w < 2) asm volatile("s_waitcnt vmcnt(4)" ::: "memory");
            else       asm volatile("s_waitcnt vmcnt(3)" ::: "memory");
        } else if (more1) {
            asm volatile("s_waitcnt vmcnt(0)" ::: "memory");
        }
        if (more1) {
            __builtin_amdgcn_s_barrier();
            __builtin_amdgcn_sched_barrier(0);
        }
        buf = nb;
    }

    // ---- epilogue: rows <256 -> V, 256..287 -> Q (log2e-scaled), 288.. -> K
#pragma unroll
    for (int cb = 0; cb < 5; ++cb) {
        int cBase = rh * 160 + rg * 80 + cb * 16 + quad * 4;
#pragma unroll
        for (int r = 0; r < 4; ++r) {
            int c = cBase + r;
            if (c < 256) {
                float bias = bv[c];
#pragma unroll
                for (int jb = 0; jb < 2; ++jb) {
                    int px = y * 64 + pxh * 32 + jb * 16 + l15;
                    vbf[((size_t)b * 256 + c) * N_PIX + px] = f2bf(acc[cb][jb][r] + bias);
                }
            } else if (c < 288) {
                float bias = bq[c - 256] * LOG2E;
#pragma unroll
                for (int jb = 0; jb < 2; ++jb) {
                    int px = y * 64 + pxh * 32 + jb * 16 + l15;
                    qt[((size_t)b * N_PIX + px) * 32 + (c - 256)] = f2bf(acc[cb][jb][r] + bias);
                }
            } else {
                float bias = bk[c - 288];
#pragma unroll
                for (int jb = 0; jb < 2; ++jb) {
                    int px = y * 64 + pxh * 32 + jb * 16 + l15;
                    kt[((size_t)b * N_PIX + px) * 32 + (c - 288)] = f2bf(acc[cb][jb][r] + bias);
                }
            }
        }
    }
}

// ---------------------------------------------------------------------------
// MFMA flash attention — j-tile 128, single barrier/iter, Pfrag ping-pong.
// qt pre-scaled by log2e; shift folded into MFMA C-init; P packed with
// v_perm_b32 (truncating bf16).
// ---------------------------------------------------------------------------
__global__ __launch_bounds__(256, 2) void fused_attn_mfma(
    const unsigned short* __restrict__ qt, const unsigned short* __restrict__ kt,
    const unsigned short* __restrict__ vbf,
    unsigned short* __restrict__ Abuf, float* __restrict__ lbuf, int iRange)
{
    const int tid  = threadIdx.x;
    const int w    = tid >> 6;
    const int lane = tid & 63;
    const int quad = lane >> 4;
    const int l15  = lane & 15;
    const int j0   = blockIdx.x * 128;
    const int b    = blockIdx.y;
    const int sp   = blockIdx.z;
    const int iBeg = sp * iRange;
    const int NI   = iRange / 64;

    const unsigned short* qtb = qt + (size_t)b * N_PIX * 32;
    const unsigned short* ktb = kt + (size_t)b * N_PIX * 32;
    const unsigned short* vb  = vbf + (size_t)b * 256 * N_PIX;

    __shared__ unsigned Pfrag[2][4096];   // 32 KB ping-pong (dwords)
    __shared__ float lred[4][128];

    bf16x8 kf[8];
#pragma unroll
    for (int jb = 0; jb < 8; ++jb)
        kf[jb] = *(const bf16x8*)&ktb[((size_t)(j0 + jb * 16 + l15)) * 32 + quad * 8];

    f32x4 acc[4][8];
#pragma unroll
    for (int cb = 0; cb < 4; ++cb)
#pragma unroll
        for (int jb = 0; jb < 8; ++jb)
            acc[cb][jb] = (f32x4){0.f, 0.f, 0.f, 0.f};

    float lpart[8] = {0.f, 0.f, 0.f, 0.f, 0.f, 0.f, 0.f, 0.f};

    const int wFrag = w >> 1;
    const int wL    = ((w & 1) << 5) + ((quad >> 1) << 4) + l15;
    const int wEl2  = (quad & 1) << 1;   // dword offset 0 or 2

    bf16x8 va[2][4];

    auto s_phase = [&](bf16x8 qa, int buf) {
#pragma unroll
        for (int jb = 0; jb < 8; ++jb) {
            f32x4 s = __builtin_amdgcn_mfma_f32_16x16x32_bf16(
                qa, kf[jb], (f32x4){-SHIFT2, -SHIFT2, -SHIFT2, -SHIFT2}, 0, 0, 0);
            float p0 = __builtin_amdgcn_exp2f(s[0]);
            float p1 = __builtin_amdgcn_exp2f(s[1]);
            float p2 = __builtin_amdgcn_exp2f(s[2]);
            float p3 = __builtin_amdgcn_exp2f(s[3]);
            lpart[jb] += (p0 + p1) + (p2 + p3);
            unsigned u0 = pack_bf16_trunc(p0, p1);
            unsigned u1 = pack_bf16_trunc(p2, p3);
            unsigned base = (((jb << 1) + wFrag) * 64 + wL) * 4 + wEl2;
            Pfrag[buf][base]     = u0;
            Pfrag[buf][base + 1] = u1;
        }
    };

    auto load_qa = [&](int i0) {
        return *(const bf16x8*)&qtb[((size_t)(i0 + w * 16 + l15)) * 32 + quad * 8];
    };
    auto load_va = [&](int i0) {
#pragma unroll
        for (int ks = 0; ks < 2; ++ks)
#pragma unroll
            for (int cb = 0; cb < 4; ++cb)
                va[ks][cb] = *(const bf16x8*)&vb[((size_t)(w * 64 + cb * 16 + l15)) * N_PIX
                                                 + i0 + ks * 32 + quad * 8];
    };

    // prologue
    load_va(iBeg);
    s_phase(load_qa(iBeg), 0);

    for (int n = 0; n < NI; ++n) {
        __syncthreads();               // P[n&1] ready for all waves
        const bool hasN = (n + 1 < NI);
        const int inext = iBeg + (n + 1) * 64;
        bf16x8 qaN;
        if (hasN) qaN = load_qa(inext);

        // ---- O(n): reads Pfrag[n&1] + va (loaded for iter n)
#pragma unroll
        for (int ks = 0; ks < 2; ++ks) {
            bf16x8 pb[8];
#pragma unroll
            for (int jb = 0; jb < 8; ++jb)
                pb[jb] = *(const bf16x8*)&Pfrag[n & 1][(((jb << 1) + ks) * 64 + lane) * 4];
#pragma unroll
            for (int cb = 0; cb < 4; ++cb)
#pragma unroll
                for (int jb = 0; jb < 8; ++jb)
                    acc[cb][jb] = __builtin_amdgcn_mfma_f32_16x16x32_bf16(
                        va[ks][cb], pb[jb], acc[cb][jb], 0, 0, 0);
        }

        // ---- prefetch va(n+1) then S(n+1) into other buffer
        if (hasN) {
            load_va(inext);
            s_phase(qaN, (n + 1) & 1);
        }
    }

    // ---- l reduction
#pragma unroll
    for (int jb = 0; jb < 8; ++jb) {
        float v = lpart[jb];
        v += __shfl_xor(v, 16, 64);
        v += __shfl_xor(v, 32, 64);
        lpart[jb] = v;
    }
    if (lane < 16) {
#pragma unroll
        for (int jb = 0; jb < 8; ++jb)
            lred[w][jb * 16 + l15] = lpart[jb];
    }
    __syncthreads();
    if (tid < 128) {
        float s = lred[0][tid] + lred[1][tid] + lred[2][tid] + lred[3][tid];
        lbuf[((size_t)sp * 4 + b) * N_PIX + j0 + tid] = s;
    }

    // ---- A partial store (bf16, unnormalized)
    unsigned short* Ab = Abuf + ((size_t)sp * 4 + b) * 256 * N_PIX;
#pragma unroll
    for (int cb = 0; cb < 4; ++cb) {
        int c = w * 64 + cb * 16 + quad * 4;
#pragma unroll
        for (int jb = 0; jb < 8; ++jb) {
            int j = j0 + jb * 16 + l15;
#pragma unroll
            for (int r = 0; r < 4; ++r)
                Ab[(size_t)(c + r) * N_PIX + j] = f2bf(acc[cb][jb][r]);
        }
    }
}

// ---------------------------------------------------------------------------
// combine: out = x + g * (sum_s A_s) / (sum_s l_s);  A is bf16.
// ---------------------------------------------------------------------------
__global__ __launch_bounds__(256) void combine_kernel(
    const unsigned short* __restrict__ A, const float* __restrict__ L,
    const float* __restrict__ x, const float* __restrict__ gamma,
    float* __restrict__ out, int split)
{
    const size_t CH = (size_t)4 * 256 * N_PIX;
    size_t flat = ((size_t)blockIdx.x * 256 + threadIdx.x) * 8;
    int j = (int)(flat & (N_PIX - 1));
    int b = (int)(flat >> 20);

    float a[8] = {0.f, 0.f, 0.f, 0.f, 0.f, 0.f, 0.f, 0.f};
    float l[8] = {0.f, 0.f, 0.f, 0.f, 0.f, 0.f, 0.f, 0.f};
    for (int s = 0; s < split; ++s) {
        ushort4 av0 = *(const ushort4*)&A[flat + (size_t)s * CH];
        ushort4 av1 = *(const ushort4*)&A[flat + (size_t)s * CH + 4];
        a[0] += bf2f(av0.x); a[1] += bf2f(av0.y); a[2] += bf2f(av0.z); a[3] += bf2f(av0.w);
        a[4] += bf2f(av1.x); a[5] += bf2f(av1.y); a[6] += bf2f(av1.z); a[7] += bf2f(av1.w);
        float4 l0 = *(const float4*)&L[((size_t)s * 4 + b) * N_PIX + j];
        float4 l1 = *(const float4*)&L[((size_t)s * 4 + b) * N_PIX + j + 4];
        l[0] += l0.x; l[1] += l0.y; l[2] += l0.z; l[3] += l0.w;
        l[4] += l1.x; l[5] += l1.y; l[6] += l1.z; l[7] += l1.w;
    }
    float g = gamma[0];
    float4 x0 = *(const float4*)&x[flat];
    float4 x1 = *(const float4*)&x[flat + 4];
    float4 o0, o1;
    o0.x = x0.x + g * a[0] / l[0];
    o0.y = x0.y + g * a[1] / l[1];
    o0.z = x0.z + g * a[2] / l[2];
    o0.w = x0.w + g * a[3] / l[3];
    o1.x = x1.x + g * a[4] / l[4];
    o1.y = x1.y + g * a[5] / l[5];
    o1.z = x1.z + g * a[6] / l[6];
    o1.w = x1.w + g * a[7] / l[7];
    *(float4*)&out[flat]     = o0;
    *(float4*)&out[flat + 4] = o1;
}

// ---------------------------------------------------------------------------
extern "C" void kernel_launch(void* const* d_in, const int* in_sizes, int n_in,
                              void* d_out, int out_size, void* d_ws, size_t ws_size,
                              hipStream_t stream)
{
    const float* x     = (const float*)d_in[0];
    const float* wq    = (const float*)d_in[1];
    const float* bq    = (const float*)d_in[2];
    const float* wk    = (const float*)d_in[3];
    const float* bk    = (const float*)d_in[4];
    const float* wv    = (const float*)d_in[5];
    const float* bv    = (const float*)d_in[6];
    const float* gamma = (const float*)d_in[7];
    float* out = (float*)d_out;

    const size_t szQTel  = (size_t)4 * N_PIX * 32;        // elements (ushort)
    const size_t szVBFel = (size_t)4 * 256 * N_PIX;
    const size_t szXBFel = (size_t)4 * N_PIX * 256;
    const size_t szWel   = (size_t)72 * 320 * 32;
    const size_t fixedB  = (2 * szQTel + szVBFel + szXBFel + szWel + 256) * 2;

    int split = 4;
    while (split > 1) {
        size_t need = fixedB
                    + (size_t)split * 4 * 256 * N_PIX * 2    // A bf16
                    + (size_t)split * 4 * N_PIX * 4;         // l fp32
        if (need <= ws_size) break;
        split >>= 1;
    }

    unsigned short* Abuf = (unsigned short*)d_ws;
    float* lbuf = (float*)(Abuf + (size_t)split * 4 * 256 * N_PIX);
    unsigned short* qt    = (unsigned short*)(lbuf + (size_t)split * 4 * N_PIX);
    unsigned short* kt    = qt + szQTel;
    unsigned short* vbf   = kt + szQTel;
    unsigned short* xbf   = vbf + szVBFel;
    unsigned short* wAll  = xbf + szXBFel;
    unsigned short* zpage = wAll + szWel;                  // 256 ushorts of 0

    x_transpose<<<dim3(N_PIX / 64, 4, 4), 256, 0, stream>>>(x, xbf);
    w_transform<<<dim3((72 * 320 * 4 + 255) / 256), 256, 0, stream>>>(
        wq, wk, wv, wAll, zpage);

    conv_gemm_v6<<<dim3(HW, 2, 4), 256, 0, stream>>>(
        xbf, wAll, bq, bk, bv, zpage, vbf, qt, kt);

    fused_attn_mfma<<<dim3(N_PIX / 128, 4, split), 256, 0, stream>>>(
        qt, kt, vbf, Abuf, lbuf, N_PIX / split);

    combine_kernel<<<dim3((4 * 256 * N_PIX) / (256 * 8)), 256, 0, stream>>>(
        Abuf, lbuf, x, gamma, out, split);
}